// Round 3
// baseline (94.289 us; speedup 1.0000x reference)
//
#include <hip/hip_runtime.h>
#include <hip/hip_bf16.h>
#include <stdint.h>

// Problem constants (ni = nt = 1024, d = 64, 2d = 128, TAU = 0.5)
#define NI   1024
#define NT   1024
#define DD   64
#define K2   128   // 2*d

typedef float f32x2 __attribute__((ext_vector_type(2)));  // for nontemporal store

// ---------------------------------------------------------------------------
// Kernel 1: precompute.
//  STE: s = sign(x)/8.  Pack sign/nonzero bits per row (posE popcount dot).
//  a_ik = b1[k] + sum_c img_s[i,c]*W1[k,c]      (b1 folded into image side)
//  b_jk =         sum_c txt_s[j,c]*W1[k,64+c]
//  Stored K-PAIR-INTERLEAVED + transposed: Ap[k>>1][i][k&1], Bp[k>>1][j][k&1]
//  so the pair kernel reads float2 (k,k+1) per lane and float4 scalar blocks.
//  rank-1: rA_i = sum_k W2[k]*a_ik ; rB_j = sum_k W2[k]*b_jk.
// Block: 128 threads (thread t = k index), 4 rows. Grid: 512.
// ---------------------------------------------------------------------------
__global__ __launch_bounds__(128) void precompute_kernel(
    const float* __restrict__ img, const float* __restrict__ txt,
    const float* __restrict__ W1,  const float* __restrict__ b1,
    const float* __restrict__ W2,
    float* __restrict__ Ap, float* __restrict__ Bp,
    float* __restrict__ rA, float* __restrict__ rB,
    unsigned long long* __restrict__ img_x, unsigned long long* __restrict__ img_m,
    unsigned long long* __restrict__ txt_x, unsigned long long* __restrict__ txt_m)
{
    const int tid = threadIdx.x;
    const int rb  = blockIdx.x * 4;            // row base in combined [0, 2048)
    const bool is_img = (rb < NI);
    const int lrb = is_img ? rb : rb - NI;
    const float* src = (is_img ? img : txt) + lrb * DD;

    __shared__ float sv[4 * 64];               // STE'd rows
    __shared__ float part[2][4];               // per-wave rank-1 partials

    // load + STE (4 rows = 256 contiguous floats)
    for (int idx = tid; idx < 4 * 64; idx += 128) {
        float x = src[idx];
        sv[idx] = (x > 0.f) ? 0.125f : ((x < 0.f) ? -0.125f : 0.f);
    }
    __syncthreads();

    // sign/nonzero packing: wave 0, lane = column
    if (tid < 64) {
        #pragma unroll
        for (int r = 0; r < 4; ++r) {
            float s = sv[r * 64 + tid];
            unsigned long long xb = __ballot(s < 0.f);
            unsigned long long mb = __ballot(s != 0.f);
            if (tid == 0) {
                if (is_img) { img_x[lrb + r] = xb; img_m[lrb + r] = mb; }
                else        { txt_x[lrb + r] = xb; txt_m[lrb + r] = mb; }
            }
        }
    }

    // h: thread t owns output index k = t; float4 LDS reads
    const int t = tid;
    const int off = is_img ? 0 : DD;
    const float* wrow = W1 + t * K2 + off;
    float h[4];
    const float hinit = is_img ? b1[t] : 0.f;
    #pragma unroll
    for (int r = 0; r < 4; ++r) h[r] = hinit;

    #pragma unroll 4
    for (int c4 = 0; c4 < DD / 4; ++c4) {
        const float4 w4 = *reinterpret_cast<const float4*>(wrow + c4 * 4);
        #pragma unroll
        for (int r = 0; r < 4; ++r) {
            const float4 s4 = *reinterpret_cast<const float4*>(&sv[r * 64 + c4 * 4]);
            h[r] = fmaf(w4.x, s4.x, h[r]);
            h[r] = fmaf(w4.y, s4.y, h[r]);
            h[r] = fmaf(w4.z, s4.z, h[r]);
            h[r] = fmaf(w4.w, s4.w, h[r]);
        }
    }

    // k-pair-interleaved transposed store: T[(t>>1)*2048 + row*2 + (t&1)]
    float* T = is_img ? Ap : Bp;
    const int tbase = (t >> 1) * 2048 + (t & 1);
    #pragma unroll
    for (int r = 0; r < 4; ++r) T[tbase + (lrb + r) * 2] = h[r];

    // rank-1 via wave shuffle reduce (sum over k = threads)
    const float w2t = W2[t];
    const int wid = tid >> 6, lane = tid & 63;
    #pragma unroll
    for (int r = 0; r < 4; ++r) {
        float v = w2t * h[r];
        v += __shfl_xor(v, 32); v += __shfl_xor(v, 16); v += __shfl_xor(v, 8);
        v += __shfl_xor(v, 4);  v += __shfl_xor(v, 2);  v += __shfl_xor(v, 1);
        if (lane == 0) part[wid][r] = v;
    }
    __syncthreads();
    if (tid < 4) {
        float s = part[0][tid] + part[1][tid];
        if (is_img) rA[lrb + tid] = s; else rB[lrb + tid] = s;
    }
}

// ---------------------------------------------------------------------------
// Kernel 2: pairwise energy.
//  negE[i,j] = 0.5*(rA_i + rB_j + sum_k W2[k]*|a_ik + b_jk|) + b2
//  posE[i,j] via popcount on packed sign bits.
//  out[p] = { exp(clip(pos/TAU,±15)), exp(clip(neg/TAU,±15)) }, p = i*NT + j.
// Block: 256 threads (lane = j), I-tile = 4. Grid: 256 i-tiles x 4 j-tiles
//  = 1024 blocks -> 4 blocks/CU, 16 waves/CU, 4 waves/SIMD.
// Inner loop per k-pair: 1 float2 vload (B), 2 scalar float4 (A), 16 VALU.
// ---------------------------------------------------------------------------
__global__ __launch_bounds__(256) void pair_kernel(
    const float* __restrict__ Ap, const float* __restrict__ Bp,
    const float* __restrict__ rA, const float* __restrict__ rB,
    const float* __restrict__ W2, const float* __restrict__ b2,
    const unsigned long long* __restrict__ img_x, const unsigned long long* __restrict__ img_m,
    const unsigned long long* __restrict__ txt_x, const unsigned long long* __restrict__ txt_m,
    const int* __restrict__ taskp,
    float* __restrict__ out)
{
    const int tid = threadIdx.x;
    const int bid = blockIdx.x;
    const int I0  = (bid >> 2) * 4;
    const int j   = (bid & 3) * 256 + tid;

    const float2* __restrict__ Bp2 = (const float2*)Bp;   // [kp][j]
    const float4* __restrict__ Ap4 = (const float4*)Ap;   // [kp][i/2]
    const float2* __restrict__ W2p = (const float2*)W2;   // [kp]

    float acc0 = 0.f, acc1 = 0.f, acc2 = 0.f, acc3 = 0.f;

    #pragma unroll 8
    for (int kp = 0; kp < K2 / 2; ++kp) {
        const float2 bv  = Bp2[kp * 1024 + j];              // coalesced 8B/lane
        const float4 a01 = Ap4[kp * 512 + (I0 >> 1)];       // uniform -> s_load
        const float4 a23 = Ap4[kp * 512 + (I0 >> 1) + 1];
        const float2 w   = W2p[kp];                         // uniform -> s_load
        float t;
        t = a01.x + bv.x; acc0 = fmaf(w.x, __builtin_fabsf(t), acc0);
        t = a01.y + bv.y; acc0 = fmaf(w.y, __builtin_fabsf(t), acc0);
        t = a01.z + bv.x; acc1 = fmaf(w.x, __builtin_fabsf(t), acc1);
        t = a01.w + bv.y; acc1 = fmaf(w.y, __builtin_fabsf(t), acc1);
        t = a23.x + bv.x; acc2 = fmaf(w.x, __builtin_fabsf(t), acc2);
        t = a23.y + bv.y; acc2 = fmaf(w.y, __builtin_fabsf(t), acc2);
        t = a23.z + bv.x; acc3 = fmaf(w.x, __builtin_fabsf(t), acc3);
        t = a23.w + bv.y; acc3 = fmaf(w.y, __builtin_fabsf(t), acc3);
    }
    float acc[4] = {acc0, acc1, acc2, acc3};

    const int task = *taskp;
    // scalar side (index i): img if task else txt; vector side (index j): other
    const unsigned long long* xi_a = task ? img_x : txt_x;
    const unsigned long long* mi_a = task ? img_m : txt_m;
    const unsigned long long* xj_a = task ? txt_x : img_x;
    const unsigned long long* mj_a = task ? txt_m : img_m;

    const unsigned long long xj = xj_a[j];
    const unsigned long long mj = mj_a[j];
    const float rBj = rB[j];
    const float b2v = b2[0];

    #pragma unroll
    for (int ii = 0; ii < 4; ++ii) {
        const int i = I0 + ii;
        const unsigned long long xi = xi_a[i];          // uniform -> s_load
        const unsigned long long mi = mi_a[i];
        const unsigned long long valid = mi & mj;
        const int nv = __popcll(valid);
        const int df = __popcll((xi ^ xj) & valid);
        const float pos = (float)(nv - 2 * df) * (1.0f / 64.0f);
        const float neg = 0.5f * (rA[i] + rBj + acc[ii]) + b2v;

        const float pe = __expf(fminf(fmaxf(pos * 2.0f, -15.0f), 15.0f));
        const float ne = __expf(fminf(fmaxf(neg * 2.0f, -15.0f), 15.0f));
        f32x2 o; o.x = pe; o.y = ne;
        __builtin_nontemporal_store(o, (f32x2*)&out[(size_t)(i * NT + j) * 2]);
    }
}

// ---------------------------------------------------------------------------
extern "C" void kernel_launch(void* const* d_in, const int* in_sizes, int n_in,
                              void* d_out, int out_size, void* d_ws, size_t ws_size,
                              hipStream_t stream) {
    const float* img = (const float*)d_in[0];
    const float* txt = (const float*)d_in[1];
    const float* W1  = (const float*)d_in[2];
    const float* b1  = (const float*)d_in[3];
    const float* W2  = (const float*)d_in[4];
    const float* b2  = (const float*)d_in[5];
    const int*  task = (const int*)d_in[6];

    // workspace layout — ~1.1 MB total
    float* Ap = (float*)d_ws;                 // [64][1024][2] k-pair interleaved
    float* Bp = Ap + K2 * 1024;               // [64][1024][2]
    float* rA = Bp + K2 * 1024;               // [1024]
    float* rB = rA + 1024;                    // [1024]
    unsigned long long* img_x = (unsigned long long*)(rB + 1024);
    unsigned long long* img_m = img_x + 1024;
    unsigned long long* txt_x = img_m + 1024;
    unsigned long long* txt_m = txt_x + 1024;

    hipLaunchKernelGGL(precompute_kernel, dim3(512), dim3(128), 0, stream,
                       img, txt, W1, b1, W2, Ap, Bp, rA, rB,
                       img_x, img_m, txt_x, txt_m);

    hipLaunchKernelGGL(pair_kernel, dim3(1024), dim3(256), 0, stream,
                       Ap, Bp, rA, rB, W2, b2,
                       img_x, img_m, txt_x, txt_m, task,
                       (float*)d_out);
}